// Round 13
// baseline (536.335 us; speedup 1.0000x reference)
//
#include <hip/hip_runtime.h>
#include <hip/hip_cooperative_groups.h>

namespace cg = cooperative_groups;

#define NN 2048
#define DIMM 256
#define HEADS 8
#define HEAD_DIM 32
#define EXPH 16
#define E_EDGES 32768
#define VDIM 512          // EXPH*HEAD_DIM
#define PW 1024           // P row width in bf16: [q 256 | k*scale 256 | vv 512]
#define SCALE_F 0.17677669529663687f
#define MASKV -1.0e9f
#define SLOTW 64          // max edges per src (Poisson mean 16; P(>64) ~ 1e-18)

typedef __attribute__((ext_vector_type(8))) short short8;
typedef __attribute__((ext_vector_type(4))) float f32x4;

__device__ __forceinline__ unsigned short f2bf(float f) {
    unsigned int u = __float_as_uint(f);
    unsigned int r = (u + 0x7FFFu + ((u >> 16) & 1u)) >> 16;   // RNE
    return (unsigned short)r;
}
__device__ __forceinline__ float bflo(unsigned int u) { return __uint_as_float(u << 16); }
__device__ __forceinline__ float bfhi(unsigned int u) { return __uint_as_float(u & 0xFFFF0000u); }

__device__ __forceinline__ int load_edge(const int* __restrict__ ei32, int is64, int idx) {
    return is64 ? ei32[2 * idx] : ei32[idx];
}

struct MegaParams {
    const float *x, *edges;
    const int* ei32;
    const float *Wq, *Wk, *Wv, *Wev, *Wexp, *Wout;
    unsigned short *xb, *eb, *Wqb, *Wkb, *Wvb, *Wevb, *Woutb, *Pb, *out2b;
    float *partialX, *partialE, *xsumG, *esumG, *colsum;
    int* slotCnt;
    unsigned int* slots;
    float* out;
};

struct SharedLap {
    unsigned int pkS[SLOTW], srtS[SLOTW];
    int liveS[SLOTW];
    float ewS[SLOTW][HEADS];
    float aS[SLOTW][EXPH];
    float WexpS[EXPH * HEADS];
    float qS[DIMM];
    float maxP[4][EXPH], sumP[4][EXPH];
    float wmaskS[EXPH], invDS[EXPH];
    int Dcnt;
};
struct SharedCvt { float lds[4][260]; };
struct SharedRed { float tree[256]; };
union SharedAll { SharedLap lap; SharedCvt cvt; SharedRed red; };

// ======================= shared device phase bodies =======================

__device__ __forceinline__ void convert_body(
    int b, int t, SharedAll& sh,
    const float* x, const float* edges, const float* Wq, const float* Wk,
    const float* Wv, const float* Wev, const float* Wout,
    unsigned short* xb, unsigned short* eb, unsigned short* Wqb, unsigned short* Wkb,
    unsigned short* Wvb, unsigned short* Wevb, unsigned short* Woutb,
    float* partialX, float* partialE)
{
    int idx = b * 256 + t;                // float4 index
    const float* src; unsigned short* dst; int loc;
    if      (idx < 131072) { src = x;     dst = xb;    loc = idx; }
    else if (idx < 262144) { src = edges; dst = eb;    loc = idx - 131072; }
    else if (idx < 278528) { src = Wq;    dst = Wqb;   loc = idx - 262144; }
    else if (idx < 294912) { src = Wk;    dst = Wkb;   loc = idx - 278528; }
    else if (idx < 327680) { src = Wv;    dst = Wvb;   loc = idx - 294912; }
    else if (idx < 360448) { src = Wev;   dst = Wevb;  loc = idx - 327680; }
    else                   { src = Wout;  dst = Woutb; loc = idx - 360448; }
    float4 v = *(const float4*)(src + (size_t)loc * 4);
    ushort4 o;
    o.x = f2bf(v.x); o.y = f2bf(v.y); o.z = f2bf(v.z); o.w = f2bf(v.w);
    *(ushort4*)(dst + (size_t)loc * 4) = o;
    if (b < 1024) {
        int lr = t >> 6;            // 0..3 local row
        int lc = (t & 63) * 4;      // col base
        sh.cvt.lds[lr][lc + 0] = v.x; sh.cvt.lds[lr][lc + 1] = v.y;
        sh.cvt.lds[lr][lc + 2] = v.z; sh.cvt.lds[lr][lc + 3] = v.w;
        __syncthreads();
        float s = sh.cvt.lds[0][t] + sh.cvt.lds[1][t] + sh.cvt.lds[2][t] + sh.cvt.lds[3][t];
        if (b < 512) partialX[(size_t)b * 256 + t] = s;
        else         partialE[(size_t)(b - 512) * 256 + t] = s;
    }
}

__device__ __forceinline__ void proj_body(
    int bx, int jb, int t,
    const unsigned short* xb, const unsigned short* eb,
    const unsigned short* Wqb, const unsigned short* Wkb,
    const unsigned short* Wvb, const unsigned short* Wevb,
    unsigned short* Pb)
{
    int lane = t & 63;
    int wave = t >> 6;
    int wm = wave >> 1;
    int wn = wave & 1;
    int rowT = bx * 32;
    int colT = jb * 64;

    const unsigned short* Wb; int wbase; int nseg = 1;
    if (jb < 4)      { Wb = Wqb; wbase = jb * 64; }
    else if (jb < 8) { Wb = Wkb; wbase = (jb - 4) * 64; }
    else             { Wb = Wvb; wbase = (jb - 8) * 64; nseg = 2; }

    int arow = rowT + wm * 16 + (lane & 15);
    int koff = (lane >> 4) * 8;

    f32x4 acc0 = {0.f, 0.f, 0.f, 0.f};
    f32x4 acc1 = {0.f, 0.f, 0.f, 0.f};

    for (int seg = 0; seg < nseg; ++seg) {
        const unsigned short* Ab = (seg == 0) ? xb : eb;
        const unsigned short* Wm = (seg == 0) ? Wb : Wevb;
        const unsigned short* ap  = Ab + (size_t)arow * DIMM + koff;
        const unsigned short* b0p = Wm + (size_t)(wbase + wn * 32 + (lane & 15)) * DIMM + koff;
        const unsigned short* b1p = b0p + 16 * DIMM;
        #pragma unroll
        for (int ks = 0; ks < 8; ks++) {
            short8 af = *(const short8*)(ap  + ks * 32);
            short8 b0 = *(const short8*)(b0p + ks * 32);
            short8 b1 = *(const short8*)(b1p + ks * 32);
            acc0 = __builtin_amdgcn_mfma_f32_16x16x32_bf16(af, b0, acc0, 0, 0, 0);
            acc1 = __builtin_amdgcn_mfma_f32_16x16x32_bf16(af, b1, acc1, 0, 0, 0);
        }
    }
    float sc = (jb >= 4 && jb < 8) ? SCALE_F : 1.0f;
    int crow0 = rowT + wm * 16 + (lane >> 4) * 4;   // C/D: col=lane&15, row=(lane>>4)*4+r
    int ccol  = colT + wn * 32 + (lane & 15);
    #pragma unroll
    for (int r = 0; r < 4; r++) {
        Pb[(size_t)(crow0 + r) * PW + ccol]      = f2bf(acc0[r] * sc);
        Pb[(size_t)(crow0 + r) * PW + ccol + 16] = f2bf(acc1[r] * sc);
    }
}

__device__ __forceinline__ void laplacian_body(
    int n, int t, SharedAll& sh,
    const int* slotCnt, const unsigned int* slots,
    const float* Wexp, const float* colsum,
    const unsigned short* Pb, unsigned short* out2b)
{
    int cnt = slotCnt[n];
    if (cnt > SLOTW) cnt = SLOTW;
    if (t == 0) sh.lap.Dcnt = 0;
    if (t < EXPH * HEADS) sh.lap.WexpS[t] = Wexp[t];
    if (t < cnt) sh.lap.pkS[t] = slots[(size_t)n * SLOTW + t];
    if (t < 128) {
        unsigned int u = ((const unsigned int*)(Pb + (size_t)n * PW))[t];
        sh.lap.qS[2 * t]     = bflo(u);
        sh.lap.qS[2 * t + 1] = bfhi(u);
    }
    __syncthreads();   // B1
    if (t < cnt) {
        unsigned int pk = sh.lap.pkS[t];
        int rank = 0;
        #pragma unroll 4
        for (int j = 0; j < cnt; j++) rank += (sh.lap.pkS[j] < pk) ? 1 : 0;
        sh.lap.srtS[rank] = pk;
    }
    __syncthreads();   // B2
    if (t < cnt) {
        unsigned int d = sh.lap.srtS[t] & 2047u;
        int live = 1;
        #pragma unroll 4
        for (int j = t + 1; j < cnt; j++)
            live &= ((sh.lap.srtS[j] & 2047u) != d) ? 1 : 0;
        sh.lap.liveS[t] = live;
        if (live) atomicAdd(&sh.lap.Dcnt, 1);
    }
    {
        int h = t & 7;
        const float* qh = sh.lap.qS + h * 32;
        for (int i = t >> 3; i < cnt; i += 32) {
            int dsti = (int)(sh.lap.srtS[i] & 2047u);
            const uint4* kr = (const uint4*)(Pb + (size_t)dsti * PW + 256 + h * 32);
            float s = 0.f;
            #pragma unroll
            for (int m = 0; m < 4; m++) {
                uint4 u = kr[m];
                const float* qq = qh + m * 8;
                s += qq[0] * bflo(u.x) + qq[1] * bfhi(u.x)
                   + qq[2] * bflo(u.y) + qq[3] * bfhi(u.y)
                   + qq[4] * bflo(u.z) + qq[5] * bfhi(u.z)
                   + qq[6] * bflo(u.w) + qq[7] * bfhi(u.w);
            }
            sh.lap.ewS[i][h] = s;
        }
    }
    __syncthreads();   // B3
    int e = t & 15;
    float Me = 0.f;
    #pragma unroll
    for (int h = 0; h < HEADS; h++) Me += MASKV * sh.lap.WexpS[e * HEADS + h];
    float m = -3.0e38f;
    for (int idx = t; idx < cnt * EXPH; idx += 256) {
        int i = idx >> 4;
        float a = 0.f;
        #pragma unroll
        for (int hh = 0; hh < HEADS; hh++) a += sh.lap.ewS[i][hh] * sh.lap.WexpS[e * HEADS + hh];
        sh.lap.aS[i][e] = a;
        if (sh.lap.liveS[i] && a > m) m = a;
    }
    m = fmaxf(m, __shfl_xor(m, 16));
    m = fmaxf(m, __shfl_xor(m, 32));
    if ((t & 0x30) == 0) sh.lap.maxP[t >> 6][e] = m;
    __syncthreads();   // B4
    float rmax = fmaxf(fmaxf(sh.lap.maxP[0][e], sh.lap.maxP[1][e]),
                       fmaxf(sh.lap.maxP[2][e], sh.lap.maxP[3][e]));
    rmax = fmaxf(rmax, Me);
    float ds = 0.f;
    for (int idx = t; idx < cnt * EXPH; idx += 256) {
        int i = idx >> 4;
        float w = sh.lap.liveS[i] ? expf(sh.lap.aS[i][e] - rmax) : 0.f;
        sh.lap.aS[i][e] = w;
        ds += w;
    }
    ds += __shfl_xor(ds, 16);
    ds += __shfl_xor(ds, 32);
    if ((t & 0x30) == 0) sh.lap.sumP[t >> 6][e] = ds;
    __syncthreads();   // B5
    if (t < EXPH) {
        float wmE = expf(Me - rmax);     // lane t has e == t
        float denom = ((sh.lap.sumP[0][t] + sh.lap.sumP[1][t])
                     + (sh.lap.sumP[2][t] + sh.lap.sumP[3][t]))
                    + (float)(NN - sh.lap.Dcnt) * wmE;
        sh.lap.wmaskS[t] = wmE / denom;
        sh.lap.invDS[t]  = 1.0f / denom;
    }
    __syncthreads();   // B6
    int e2 = t >> 4;
    float wm = sh.lap.wmaskS[e2];
    float invD = sh.lap.invDS[e2];
    unsigned int uv = ((const unsigned int*)(Pb + (size_t)n * PW + 512))[t];
    float2 cv = ((const float2*)colsum)[t];
    float ax = bflo(uv) - wm * cv.x;
    float ay = bfhi(uv) - wm * cv.y;
    int i = 0;
    for (; i + 8 <= cnt; i += 8) {
        unsigned int u[8];
        float w[8];
        #pragma unroll
        for (int j = 0; j < 8; j++)
            u[j] = ((const unsigned int*)(Pb + (size_t)(sh.lap.srtS[i + j] & 2047u) * PW + 512))[t];
        #pragma unroll
        for (int j = 0; j < 8; j++)
            w[j] = sh.lap.liveS[i + j] ? (wm - sh.lap.aS[i + j][e2] * invD) : 0.f;
        #pragma unroll
        for (int j = 0; j < 8; j++) { ax += w[j] * bflo(u[j]); ay += w[j] * bfhi(u[j]); }
    }
    for (; i < cnt; i++) {
        unsigned int ub = ((const unsigned int*)(Pb + (size_t)(sh.lap.srtS[i] & 2047u) * PW + 512))[t];
        float w = sh.lap.liveS[i] ? (wm - sh.lap.aS[i][e2] * invD) : 0.f;
        ax += w * bflo(ub); ay += w * bfhi(ub);
    }
    unsigned int* o = (unsigned int*)(out2b + (size_t)n * VDIM);
    o[t] = (unsigned int)f2bf(ax) | ((unsigned int)f2bf(ay) << 16);
}

__device__ __forceinline__ void outgemm_body(
    int bx, int by, int t,
    const unsigned short* Ab, const unsigned short* Wb, float* C)
{
    int lane = t & 63;
    int wn = t >> 6;        // 0..3
    int rowT = bx * 16;
    int colT = by * 64 + wn * 16;

    int arow = rowT + (lane & 15);
    int koff = (lane >> 4) * 8;

    f32x4 accA = {0.f, 0.f, 0.f, 0.f};
    f32x4 accB = {0.f, 0.f, 0.f, 0.f};

    const unsigned short* ap = Ab + (size_t)arow * VDIM + koff;
    const unsigned short* bp = Wb + (size_t)(colT + (lane & 15)) * VDIM + koff;
    #pragma unroll
    for (int ks = 0; ks < 8; ks++) {
        short8 afA = *(const short8*)(ap + ks * 32);
        short8 bfA = *(const short8*)(bp + ks * 32);
        accA = __builtin_amdgcn_mfma_f32_16x16x32_bf16(afA, bfA, accA, 0, 0, 0);
        short8 afB = *(const short8*)(ap + (ks + 8) * 32);
        short8 bfB = *(const short8*)(bp + (ks + 8) * 32);
        accB = __builtin_amdgcn_mfma_f32_16x16x32_bf16(afB, bfB, accB, 0, 0, 0);
    }
    int crow0 = rowT + (lane >> 4) * 4;
    int ccol  = colT + (lane & 15);
    #pragma unroll
    for (int r = 0; r < 4; r++)
        C[(size_t)(crow0 + r) * DIMM + ccol] = accA[r] + accB[r];
}

// ======================= cooperative mega-kernel =======================

__global__ __launch_bounds__(256, 4) void mega_kernel(MegaParams P) {
    cg::grid_group grid = cg::this_grid();
    __shared__ SharedAll sh;
    int blk = blockIdx.x;
    int t = threadIdx.x;

    // ---- P0: convert + column partials + slotCnt zero ----
    for (int it = 0; it < 2; ++it) {
        int b = blk + it * 1024;
        if (b >= 1544) continue;
        if (b >= 1536) { P.slotCnt[(b - 1536) * 256 + t] = 0; continue; }
        convert_body(b, t, sh, P.x, P.edges, P.Wq, P.Wk, P.Wv, P.Wev, P.Wout,
                     P.xb, P.eb, P.Wqb, P.Wkb, P.Wvb, P.Wevb, P.Woutb,
                     P.partialX, P.partialE);
    }
    grid.sync();

    // ---- P1: xsum/esum column trees (512 blocks) + edge scatter (64 blocks) ----
    if (blk < 512) {
        const float* part = (blk < 256) ? P.partialX : P.partialE;
        int c = blk & 255;
        sh.red.tree[t] = part[(size_t)t * 256 + c] + part[(size_t)(t + 256) * 256 + c];
        __syncthreads();
        for (int w = 128; w > 0; w >>= 1) {
            if (t < w) sh.red.tree[t] += sh.red.tree[t + w];
            __syncthreads();
        }
        if (t == 0) {
            if (blk < 256) P.xsumG[c] = sh.red.tree[0];
            else           P.esumG[c] = sh.red.tree[0];
        }
    } else if (blk < 576) {
        int bx = blk - 512;   // 0..63
        int nz = __syncthreads_count(P.ei32[2 * t + 1] != 0);
        int is64 = (nz == 0);
        #pragma unroll
        for (int r = 0; r < 2; r++) {
            int p = bx * 512 + r * 256 + t;
            int s = load_edge(P.ei32, is64, p);
            int d = load_edge(P.ei32, is64, E_EDGES + p);
            int pos = atomicAdd(&P.slotCnt[s], 1);
            if (pos < SLOTW)
                P.slots[(size_t)s * SLOTW + pos] = (unsigned int)(p * 2048 + d);  // id-major
        }
    }
    grid.sync();

    // ---- P2: proj MFMA (all 1024 blocks, 64x16 geometry) + colsum GEMV (blocks<512) ----
    proj_body(blk & 63, blk >> 6, t, P.xb, P.eb, P.Wqb, P.Wkb, P.Wvb, P.Wevb, P.Pb);
    if (blk < 512) {
        int c = blk;    // 0..511
        float v = P.xsumG[t] * P.Wv[(size_t)c * 256 + t]
                + P.esumG[t] * P.Wev[(size_t)c * 256 + t];
        sh.red.tree[t] = v;
        __syncthreads();
        for (int w = 128; w > 0; w >>= 1) {
            if (t < w) sh.red.tree[t] += sh.red.tree[t + w];
            __syncthreads();
        }
        if (t == 0) P.colsum[c] = sh.red.tree[0];
    }
    grid.sync();

    // ---- P3: laplacian, 2 nodes per block ----
    for (int rep = 0; rep < 2; ++rep) {
        __syncthreads();
        laplacian_body(blk * 2 + rep, t, sh, P.slotCnt, P.slots, P.Wexp,
                       P.colsum, P.Pb, P.out2b);
    }
    grid.sync();

    // ---- P4: final GEMM (blocks < 512, 128x4 geometry) ----
    if (blk < 512)
        outgemm_body(blk & 127, blk >> 7, t, P.out2b, P.Woutb, P.out);
}

// ======================= fallback kernels (r12 structure) =======================

__global__ __launch_bounds__(256) void convert_init_kernel(
    const float* __restrict__ x, const float* __restrict__ edges,
    const float* __restrict__ Wq, const float* __restrict__ Wk,
    const float* __restrict__ Wv, const float* __restrict__ Wev,
    const float* __restrict__ Wout,
    unsigned short* __restrict__ xb, unsigned short* __restrict__ eb,
    unsigned short* __restrict__ Wqb, unsigned short* __restrict__ Wkb,
    unsigned short* __restrict__ Wvb, unsigned short* __restrict__ Wevb,
    unsigned short* __restrict__ Woutb,
    float* __restrict__ partialX, float* __restrict__ partialE,
    int* __restrict__ slotCnt)
{
    __shared__ SharedAll sh;
    int b = blockIdx.x;
    int t = threadIdx.x;
    if (b >= 1536) { slotCnt[(b - 1536) * 256 + t] = 0; return; }
    convert_body(b, t, sh, x, edges, Wq, Wk, Wv, Wev, Wout,
                 xb, eb, Wqb, Wkb, Wvb, Wevb, Woutb, partialX, partialE);
}

__global__ __launch_bounds__(256) void red_scatter_kernel(
    const float* __restrict__ partialX, const float* __restrict__ partialE,
    float* __restrict__ xsumG, float* __restrict__ esumG,
    const int* __restrict__ ei32, int* __restrict__ slotCnt,
    unsigned int* __restrict__ slots)
{
    __shared__ SharedAll sh;
    int blk = blockIdx.x;
    int t = threadIdx.x;
    if (blk < 512) {
        const float* part = (blk < 256) ? partialX : partialE;
        int c = blk & 255;
        sh.red.tree[t] = part[(size_t)t * 256 + c] + part[(size_t)(t + 256) * 256 + c];
        __syncthreads();
        for (int w = 128; w > 0; w >>= 1) {
            if (t < w) sh.red.tree[t] += sh.red.tree[t + w];
            __syncthreads();
        }
        if (t == 0) {
            if (blk < 256) xsumG[c] = sh.red.tree[0];
            else           esumG[c] = sh.red.tree[0];
        }
    } else {
        int bx = blk - 512;
        int nz = __syncthreads_count(ei32[2 * t + 1] != 0);
        int is64 = (nz == 0);
        #pragma unroll
        for (int r = 0; r < 2; r++) {
            int p = bx * 512 + r * 256 + t;
            int s = load_edge(ei32, is64, p);
            int d = load_edge(ei32, is64, E_EDGES + p);
            int pos = atomicAdd(&slotCnt[s], 1);
            if (pos < SLOTW)
                slots[(size_t)s * SLOTW + pos] = (unsigned int)(p * 2048 + d);
        }
    }
}

__global__ __launch_bounds__(256) void proj_gemv_kernel(
    const unsigned short* __restrict__ xb, const unsigned short* __restrict__ eb,
    const unsigned short* __restrict__ Wqb, const unsigned short* __restrict__ Wkb,
    const unsigned short* __restrict__ Wvb, const unsigned short* __restrict__ Wevb,
    unsigned short* __restrict__ Pb,
    const float* __restrict__ xsumG, const float* __restrict__ esumG,
    const float* __restrict__ Wv32, const float* __restrict__ Wev32,
    float* __restrict__ colsum)
{
    __shared__ SharedAll sh;
    int blk = blockIdx.x;
    int t = threadIdx.x;
    proj_body(blk & 63, blk >> 6, t, xb, eb, Wqb, Wkb, Wvb, Wevb, Pb);
    if (blk < 512) {
        int c = blk;
        float v = xsumG[t] * Wv32[(size_t)c * 256 + t] + esumG[t] * Wev32[(size_t)c * 256 + t];
        sh.red.tree[t] = v;
        __syncthreads();
        for (int w = 128; w > 0; w >>= 1) {
            if (t < w) sh.red.tree[t] += sh.red.tree[t + w];
            __syncthreads();
        }
        if (t == 0) colsum[c] = sh.red.tree[0];
    }
}

__global__ __launch_bounds__(256) void laplacian_kernel(
    const int* __restrict__ slotCnt, const unsigned int* __restrict__ slots,
    const float* __restrict__ Wexp, const float* __restrict__ colsum,
    const unsigned short* __restrict__ Pb, unsigned short* __restrict__ out2b)
{
    __shared__ SharedAll sh;
    laplacian_body(blockIdx.x, threadIdx.x, sh, slotCnt, slots, Wexp, colsum, Pb, out2b);
}

__global__ __launch_bounds__(256) void outgemm_mfma_kernel(
    const unsigned short* __restrict__ Ab, const unsigned short* __restrict__ Wb,
    float* __restrict__ C)
{
    outgemm_body(blockIdx.x, blockIdx.y, threadIdx.x, Ab, Wb, C);
}

// ======================= launch =======================

extern "C" void kernel_launch(void* const* d_in, const int* in_sizes, int n_in,
                              void* d_out, int out_size, void* d_ws, size_t ws_size,
                              hipStream_t stream) {
    const float* x     = (const float*)d_in[0];
    const float* edges = (const float*)d_in[1];
    const int*   ei32  = (const int*)d_in[2];
    const float* Wq    = (const float*)d_in[3];
    const float* Wk    = (const float*)d_in[4];
    const float* Wv    = (const float*)d_in[5];
    const float* Wev   = (const float*)d_in[6];
    const float* Wexp  = (const float*)d_in[7];
    const float* Wout  = (const float*)d_in[8];
    float* out = (float*)d_out;

    char* ws = (char*)d_ws;
    size_t off = 0;
    auto alloc = [&](size_t bytes) -> void* {
        void* p = ws + off;
        off = (off + bytes + 255) & ~(size_t)255;
        return p;
    };
    unsigned short* Pb    = (unsigned short*)alloc((size_t)NN * PW * 2);   // 4 MB
    float* partialX       = (float*)alloc((size_t)512 * 256 * 4);          // 512 KB
    float* partialE       = (float*)alloc((size_t)512 * 256 * 4);          // 512 KB
    float* xsumG          = (float*)alloc(256 * 4);
    float* esumG          = (float*)alloc(256 * 4);
    float* colsum         = (float*)alloc(VDIM * 4);
    unsigned short* xb    = (unsigned short*)alloc((size_t)NN * DIMM * 2);
    unsigned short* eb    = (unsigned short*)alloc((size_t)NN * DIMM * 2);
    unsigned short* Wqb   = (unsigned short*)alloc((size_t)DIMM * DIMM * 2);
    unsigned short* Wkb   = (unsigned short*)alloc((size_t)DIMM * DIMM * 2);
    unsigned short* Wvb   = (unsigned short*)alloc((size_t)VDIM * DIMM * 2);
    unsigned short* Wevb  = (unsigned short*)alloc((size_t)VDIM * DIMM * 2);
    unsigned short* Woutb = (unsigned short*)alloc((size_t)DIMM * VDIM * 2);
    unsigned short* out2b = (unsigned short*)alloc((size_t)NN * VDIM * 2);
    int* slotCnt          = (int*)alloc(NN * 4);
    unsigned int* slots   = (unsigned int*)alloc((size_t)NN * SLOTW * 4);  // 512 KB
    (void)ws_size; (void)in_sizes; (void)n_in; (void)out_size;

    MegaParams P;
    P.x = x; P.edges = edges; P.ei32 = ei32;
    P.Wq = Wq; P.Wk = Wk; P.Wv = Wv; P.Wev = Wev; P.Wexp = Wexp; P.Wout = Wout;
    P.xb = xb; P.eb = eb; P.Wqb = Wqb; P.Wkb = Wkb; P.Wvb = Wvb; P.Wevb = Wevb;
    P.Woutb = Woutb; P.Pb = Pb; P.out2b = out2b;
    P.partialX = partialX; P.partialE = partialE;
    P.xsumG = xsumG; P.esumG = esumG; P.colsum = colsum;
    P.slotCnt = slotCnt; P.slots = slots; P.out = out;

    void* args[] = { &P };
    hipError_t err = hipLaunchCooperativeKernel((void*)mega_kernel,
                                                dim3(1024), dim3(256),
                                                args, 0, stream);
    if (err != hipSuccess) {
        // fallback: equivalent 5-kernel pipeline
        convert_init_kernel<<<1544, 256, 0, stream>>>(x, edges, Wq, Wk, Wv, Wev, Wout,
                                                      xb, eb, Wqb, Wkb, Wvb, Wevb, Woutb,
                                                      partialX, partialE, slotCnt);
        red_scatter_kernel<<<576, 256, 0, stream>>>(partialX, partialE, xsumG, esumG,
                                                    ei32, slotCnt, slots);
        proj_gemv_kernel<<<1024, 256, 0, stream>>>(xb, eb, Wqb, Wkb, Wvb, Wevb, Pb,
                                                   xsumG, esumG, Wv, Wev, colsum);
        laplacian_kernel<<<NN, 256, 0, stream>>>(slotCnt, slots, Wexp, colsum, Pb, out2b);
        outgemm_mfma_kernel<<<dim3(128, 4), 256, 0, stream>>>(out2b, Woutb, out);
    }
}

// Round 14
// 57.751 us; speedup vs baseline: 9.2870x; 9.2870x over previous
//
#include <hip/hip_runtime.h>

#define NN 2048
#define DIMM 256
#define HEADS 8
#define HEAD_DIM 32
#define EXPH 16
#define E_EDGES 32768
#define VDIM 512          // EXPH*HEAD_DIM
#define PW 1024           // P row width in bf16: [q 256 | k*scale 256 | vv 512]
#define SCALE_F 0.17677669529663687f
#define MASKV -1.0e9f
#define SLOTW 64          // max edges per src (Poisson mean 16; P(>64) ~ 1e-18)

typedef __attribute__((ext_vector_type(8))) short short8;
typedef __attribute__((ext_vector_type(4))) float f32x4;

__device__ __forceinline__ unsigned short f2bf(float f) {
    unsigned int u = __float_as_uint(f);
    unsigned int r = (u + 0x7FFFu + ((u >> 16) & 1u)) >> 16;   // RNE
    return (unsigned short)r;
}
__device__ __forceinline__ float bflo(unsigned int u) { return __uint_as_float(u << 16); }
__device__ __forceinline__ float bfhi(unsigned int u) { return __uint_as_float(u & 0xFFFF0000u); }

__device__ __forceinline__ int load_edge(const int* __restrict__ ei32, int is64, int idx) {
    return is64 ? ei32[2 * idx] : ei32[idx];
}

// ---------- K1: f32->bf16 convert + x/edges column partials + slotCnt zero ----------
__global__ __launch_bounds__(256) void convert_init_kernel(
    const float* __restrict__ x, const float* __restrict__ edges,
    const float* __restrict__ Wq, const float* __restrict__ Wk,
    const float* __restrict__ Wv, const float* __restrict__ Wev,
    const float* __restrict__ Wout,
    unsigned short* __restrict__ xb, unsigned short* __restrict__ eb,
    unsigned short* __restrict__ Wqb, unsigned short* __restrict__ Wkb,
    unsigned short* __restrict__ Wvb, unsigned short* __restrict__ Wevb,
    unsigned short* __restrict__ Woutb,
    float* __restrict__ partialX, float* __restrict__ partialE,
    int* __restrict__ slotCnt)
{
    __shared__ float lds[4][260];
    int b = blockIdx.x;
    int t = threadIdx.x;
    if (b >= 1536) {
        slotCnt[(b - 1536) * 256 + t] = 0;   // 8 blocks cover 2048
        return;
    }
    int idx = b * 256 + t;                // float4 index
    const float* src; unsigned short* dst; int loc;
    if      (idx < 131072) { src = x;     dst = xb;    loc = idx; }
    else if (idx < 262144) { src = edges; dst = eb;    loc = idx - 131072; }
    else if (idx < 278528) { src = Wq;    dst = Wqb;   loc = idx - 262144; }
    else if (idx < 294912) { src = Wk;    dst = Wkb;   loc = idx - 278528; }
    else if (idx < 327680) { src = Wv;    dst = Wvb;   loc = idx - 294912; }
    else if (idx < 360448) { src = Wev;   dst = Wevb;  loc = idx - 327680; }
    else                   { src = Wout;  dst = Woutb; loc = idx - 360448; }
    float4 v = *(const float4*)(src + (size_t)loc * 4);
    ushort4 o;
    o.x = f2bf(v.x); o.y = f2bf(v.y); o.z = f2bf(v.z); o.w = f2bf(v.w);
    *(ushort4*)(dst + (size_t)loc * 4) = o;
    if (b < 1024) {
        int lr = t >> 6;            // 0..3 local row
        int lc = (t & 63) * 4;      // col base
        lds[lr][lc + 0] = v.x; lds[lr][lc + 1] = v.y;
        lds[lr][lc + 2] = v.z; lds[lr][lc + 3] = v.w;
        __syncthreads();
        float s = lds[0][t] + lds[1][t] + lds[2][t] + lds[3][t];
        if (b < 512) partialX[(size_t)b * 256 + t] = s;
        else         partialE[(size_t)(b - 512) * 256 + t] = s;
    }
}

// ---------- K2: xsum/esum column trees (blocks 0..511) + edge scatter (512..575) ----------
__global__ __launch_bounds__(256) void red_scatter_kernel(
    const float* __restrict__ partialX, const float* __restrict__ partialE,
    float* __restrict__ xsumG, float* __restrict__ esumG,
    const int* __restrict__ ei32, int* __restrict__ slotCnt,
    unsigned int* __restrict__ slots)
{
    __shared__ float tree[256];
    int blk = blockIdx.x;
    int t = threadIdx.x;
    if (blk < 512) {
        const float* part = (blk < 256) ? partialX : partialE;
        int c = blk & 255;
        tree[t] = part[(size_t)t * 256 + c] + part[(size_t)(t + 256) * 256 + c];
        __syncthreads();
        for (int w = 128; w > 0; w >>= 1) {
            if (t < w) tree[t] += tree[t + w];
            __syncthreads();
        }
        if (t == 0) {
            if (blk < 256) xsumG[c] = tree[0];
            else           esumG[c] = tree[0];
        }
    } else {
        int bx = blk - 512;   // 0..63
        int nz = __syncthreads_count(ei32[2 * t + 1] != 0);
        int is64 = (nz == 0);
        #pragma unroll
        for (int r = 0; r < 2; r++) {
            int p = bx * 512 + r * 256 + t;
            int s = load_edge(ei32, is64, p);
            int d = load_edge(ei32, is64, E_EDGES + p);
            int pos = atomicAdd(&slotCnt[s], 1);
            if (pos < SLOTW)
                slots[(size_t)s * SLOTW + pos] = (unsigned int)(p * 2048 + d);  // id-major
        }
    }
}

// ---------- K3: proj via MFMA (1024 blocks, 64x16 geometry) + colsum GEMV (blocks<512) ----------
__global__ __launch_bounds__(256) void proj_gemv_kernel(
    const unsigned short* __restrict__ xb, const unsigned short* __restrict__ eb,
    const unsigned short* __restrict__ Wqb, const unsigned short* __restrict__ Wkb,
    const unsigned short* __restrict__ Wvb, const unsigned short* __restrict__ Wevb,
    unsigned short* __restrict__ Pb,
    const float* __restrict__ xsumG, const float* __restrict__ esumG,
    const float* __restrict__ Wv32, const float* __restrict__ Wev32,
    float* __restrict__ colsum)
{
    __shared__ float tree[256];
    int blk = blockIdx.x;
    int t = threadIdx.x;
    int bx = blk & 63;
    int jb = blk >> 6;

    // ---- proj: block tile 32x64, 4 waves (2x2), wave tile 16x32 ----
    {
        int lane = t & 63;
        int wave = t >> 6;
        int wm = wave >> 1;
        int wn = wave & 1;
        int rowT = bx * 32;
        int colT = jb * 64;

        const unsigned short* Wb; int wbase; int nseg = 1;
        if (jb < 4)      { Wb = Wqb; wbase = jb * 64; }
        else if (jb < 8) { Wb = Wkb; wbase = (jb - 4) * 64; }
        else             { Wb = Wvb; wbase = (jb - 8) * 64; nseg = 2; }

        int arow = rowT + wm * 16 + (lane & 15);
        int koff = (lane >> 4) * 8;

        f32x4 acc0 = {0.f, 0.f, 0.f, 0.f};
        f32x4 acc1 = {0.f, 0.f, 0.f, 0.f};

        for (int seg = 0; seg < nseg; ++seg) {
            const unsigned short* Ab = (seg == 0) ? xb : eb;
            const unsigned short* Wm = (seg == 0) ? Wb : Wevb;
            const unsigned short* ap  = Ab + (size_t)arow * DIMM + koff;
            const unsigned short* b0p = Wm + (size_t)(wbase + wn * 32 + (lane & 15)) * DIMM + koff;
            const unsigned short* b1p = b0p + 16 * DIMM;
            #pragma unroll
            for (int ks = 0; ks < 8; ks++) {
                short8 af = *(const short8*)(ap  + ks * 32);
                short8 b0 = *(const short8*)(b0p + ks * 32);
                short8 b1 = *(const short8*)(b1p + ks * 32);
                acc0 = __builtin_amdgcn_mfma_f32_16x16x32_bf16(af, b0, acc0, 0, 0, 0);
                acc1 = __builtin_amdgcn_mfma_f32_16x16x32_bf16(af, b1, acc1, 0, 0, 0);
            }
        }
        float sc = (jb >= 4 && jb < 8) ? SCALE_F : 1.0f;
        int crow0 = rowT + wm * 16 + (lane >> 4) * 4;   // C/D: col=lane&15, row=(lane>>4)*4+r
        int ccol  = colT + wn * 32 + (lane & 15);
        #pragma unroll
        for (int r = 0; r < 4; r++) {
            Pb[(size_t)(crow0 + r) * PW + ccol]      = f2bf(acc0[r] * sc);
            Pb[(size_t)(crow0 + r) * PW + ccol + 16] = f2bf(acc1[r] * sc);
        }
    }
    // ---- colsum GEMV: colsum[c] = xsum . Wv32[c,:] + esum . Wev32[c,:] ----
    if (blk < 512) {
        int c = blk;    // 0..511
        float v = xsumG[t] * Wv32[(size_t)c * 256 + t]
                + esumG[t] * Wev32[(size_t)c * 256 + t];
        tree[t] = v;
        __syncthreads();
        for (int w = 128; w > 0; w >>= 1) {
            if (t < w) tree[t] += tree[t + w];
            __syncthreads();
        }
        if (t == 0) colsum[c] = tree[0];
    }
}

// ---------- K4: fused edge-dot + head-expand + wave-parallel softmax + Laplacian apply ----------
__global__ __launch_bounds__(256) void laplacian_kernel(
    const int* __restrict__ slotCnt, const unsigned int* __restrict__ slots,
    const float* __restrict__ Wexp, const float* __restrict__ colsum,
    const unsigned short* __restrict__ Pb, unsigned short* __restrict__ out2b)
{
    __shared__ unsigned int pkS[SLOTW], srtS[SLOTW];
    __shared__ int liveS[SLOTW];
    __shared__ float ewS[SLOTW][HEADS];
    __shared__ float aS[SLOTW][EXPH];
    __shared__ float WexpS[EXPH * HEADS];
    __shared__ float qS[DIMM];
    __shared__ float maxP[4][EXPH], sumP[4][EXPH];
    __shared__ float wmaskS[EXPH], invDS[EXPH];
    __shared__ int Dcnt;
    int n = blockIdx.x;
    int t = threadIdx.x;
    int cnt = slotCnt[n];
    if (cnt > SLOTW) cnt = SLOTW;
    if (t == 0) Dcnt = 0;
    if (t < EXPH * HEADS) WexpS[t] = Wexp[t];
    if (t < cnt) pkS[t] = slots[(size_t)n * SLOTW + t];
    if (t < 128) {
        unsigned int u = ((const unsigned int*)(Pb + (size_t)n * PW))[t];
        qS[2 * t]     = bflo(u);
        qS[2 * t + 1] = bfhi(u);
    }
    __syncthreads();   // B1
    if (t < cnt) {
        unsigned int pk = pkS[t];
        int rank = 0;
        #pragma unroll 4
        for (int j = 0; j < cnt; j++) rank += (pkS[j] < pk) ? 1 : 0;
        srtS[rank] = pk;
    }
    __syncthreads();   // B2
    if (t < cnt) {
        unsigned int d = srtS[t] & 2047u;
        int live = 1;
        #pragma unroll 4
        for (int j = t + 1; j < cnt; j++)
            live &= ((srtS[j] & 2047u) != d) ? 1 : 0;
        liveS[t] = live;
        if (live) atomicAdd(&Dcnt, 1);
    }
    {
        int h = t & 7;
        const float* qh = qS + h * 32;
        for (int i = t >> 3; i < cnt; i += 32) {
            int dsti = (int)(srtS[i] & 2047u);
            const uint4* kr = (const uint4*)(Pb + (size_t)dsti * PW + 256 + h * 32);
            float s = 0.f;
            #pragma unroll
            for (int m = 0; m < 4; m++) {
                uint4 u = kr[m];
                const float* qq = qh + m * 8;
                s += qq[0] * bflo(u.x) + qq[1] * bfhi(u.x)
                   + qq[2] * bflo(u.y) + qq[3] * bfhi(u.y)
                   + qq[4] * bflo(u.z) + qq[5] * bfhi(u.z)
                   + qq[6] * bflo(u.w) + qq[7] * bfhi(u.w);
            }
            ewS[i][h] = s;
        }
    }
    __syncthreads();   // B3
    int e = t & 15;
    float Me = 0.f;
    #pragma unroll
    for (int h = 0; h < HEADS; h++) Me += MASKV * WexpS[e * HEADS + h];
    float m = -3.0e38f;
    for (int idx = t; idx < cnt * EXPH; idx += 256) {
        int i = idx >> 4;
        float a = 0.f;
        #pragma unroll
        for (int hh = 0; hh < HEADS; hh++) a += ewS[i][hh] * WexpS[e * HEADS + hh];
        aS[i][e] = a;
        if (liveS[i] && a > m) m = a;
    }
    m = fmaxf(m, __shfl_xor(m, 16));
    m = fmaxf(m, __shfl_xor(m, 32));
    if ((t & 0x30) == 0) maxP[t >> 6][e] = m;
    __syncthreads();   // B4
    float rmax = fmaxf(fmaxf(maxP[0][e], maxP[1][e]), fmaxf(maxP[2][e], maxP[3][e]));
    rmax = fmaxf(rmax, Me);
    float ds = 0.f;
    for (int idx = t; idx < cnt * EXPH; idx += 256) {
        int i = idx >> 4;
        float w = liveS[i] ? expf(aS[i][e] - rmax) : 0.f;
        aS[i][e] = w;
        ds += w;
    }
    ds += __shfl_xor(ds, 16);
    ds += __shfl_xor(ds, 32);
    if ((t & 0x30) == 0) sumP[t >> 6][e] = ds;
    __syncthreads();   // B5
    if (t < EXPH) {
        float wmE = expf(Me - rmax);     // lane t has e == t
        float denom = ((sumP[0][t] + sumP[1][t]) + (sumP[2][t] + sumP[3][t]))
                    + (float)(NN - Dcnt) * wmE;
        wmaskS[t] = wmE / denom;
        invDS[t]  = 1.0f / denom;
    }
    __syncthreads();   // B6
    int e2 = t >> 4;
    float wm = wmaskS[e2];
    float invD = invDS[e2];
    unsigned int uv = ((const unsigned int*)(Pb + (size_t)n * PW + 512))[t];
    float2 cv = ((const float2*)colsum)[t];
    float ax = bflo(uv) - wm * cv.x;
    float ay = bfhi(uv) - wm * cv.y;
    int i = 0;
    for (; i + 8 <= cnt; i += 8) {
        unsigned int u[8];
        float w[8];
        #pragma unroll
        for (int j = 0; j < 8; j++)
            u[j] = ((const unsigned int*)(Pb + (size_t)(srtS[i + j] & 2047u) * PW + 512))[t];
        #pragma unroll
        for (int j = 0; j < 8; j++)
            w[j] = liveS[i + j] ? (wm - aS[i + j][e2] * invD) : 0.f;
        #pragma unroll
        for (int j = 0; j < 8; j++) { ax += w[j] * bflo(u[j]); ay += w[j] * bfhi(u[j]); }
    }
    for (; i < cnt; i++) {
        unsigned int ub = ((const unsigned int*)(Pb + (size_t)(srtS[i] & 2047u) * PW + 512))[t];
        float w = liveS[i] ? (wm - aS[i][e2] * invD) : 0.f;
        ax += w * bflo(ub); ay += w * bfhi(ub);
    }
    unsigned int* o = (unsigned int*)(out2b + (size_t)n * VDIM);
    o[t] = (unsigned int)f2bf(ax) | ((unsigned int)f2bf(ay) << 16);
}

// ---------- K5: final GEMM via MFMA, dual accumulator chains ----------
__global__ __launch_bounds__(256) void outgemm_mfma_kernel(
    const unsigned short* __restrict__ Ab, const unsigned short* __restrict__ Wb,
    float* __restrict__ C)
{
    int t = threadIdx.x;
    int lane = t & 63;
    int wn = t >> 6;        // 0..3
    int rowT = blockIdx.x * 16;
    int colT = blockIdx.y * 64 + wn * 16;

    int arow = rowT + (lane & 15);
    int koff = (lane >> 4) * 8;

    f32x4 accA = {0.f, 0.f, 0.f, 0.f};
    f32x4 accB = {0.f, 0.f, 0.f, 0.f};

    const unsigned short* ap = Ab + (size_t)arow * VDIM + koff;
    const unsigned short* bp = Wb + (size_t)(colT + (lane & 15)) * VDIM + koff;
    #pragma unroll
    for (int ks = 0; ks < 8; ks++) {
        short8 afA = *(const short8*)(ap + ks * 32);
        short8 bfA = *(const short8*)(bp + ks * 32);
        accA = __builtin_amdgcn_mfma_f32_16x16x32_bf16(afA, bfA, accA, 0, 0, 0);
        short8 afB = *(const short8*)(ap + (ks + 8) * 32);
        short8 bfB = *(const short8*)(bp + (ks + 8) * 32);
        accB = __builtin_amdgcn_mfma_f32_16x16x32_bf16(afB, bfB, accB, 0, 0, 0);
    }
    int crow0 = rowT + (lane >> 4) * 4;
    int ccol  = colT + (lane & 15);
    #pragma unroll
    for (int r = 0; r < 4; r++)
        C[(size_t)(crow0 + r) * DIMM + ccol] = accA[r] + accB[r];
}

extern "C" void kernel_launch(void* const* d_in, const int* in_sizes, int n_in,
                              void* d_out, int out_size, void* d_ws, size_t ws_size,
                              hipStream_t stream) {
    const float* x     = (const float*)d_in[0];
    const float* edges = (const float*)d_in[1];
    const int*   ei32  = (const int*)d_in[2];
    const float* Wq    = (const float*)d_in[3];
    const float* Wk    = (const float*)d_in[4];
    const float* Wv    = (const float*)d_in[5];
    const float* Wev   = (const float*)d_in[6];
    const float* Wexp  = (const float*)d_in[7];
    const float* Wout  = (const float*)d_in[8];
    float* out = (float*)d_out;

    char* ws = (char*)d_ws;
    size_t off = 0;
    auto alloc = [&](size_t bytes) -> void* {
        void* p = ws + off;
        off = (off + bytes + 255) & ~(size_t)255;
        return p;
    };
    unsigned short* Pb    = (unsigned short*)alloc((size_t)NN * PW * 2);   // 4 MB
    float* partialX       = (float*)alloc((size_t)512 * 256 * 4);          // 512 KB
    float* partialE       = (float*)alloc((size_t)512 * 256 * 4);          // 512 KB
    float* xsumG          = (float*)alloc(256 * 4);
    float* esumG          = (float*)alloc(256 * 4);
    float* colsum         = (float*)alloc(VDIM * 4);
    unsigned short* xb    = (unsigned short*)alloc((size_t)NN * DIMM * 2);
    unsigned short* eb    = (unsigned short*)alloc((size_t)NN * DIMM * 2);
    unsigned short* Wqb   = (unsigned short*)alloc((size_t)DIMM * DIMM * 2);
    unsigned short* Wkb   = (unsigned short*)alloc((size_t)DIMM * DIMM * 2);
    unsigned short* Wvb   = (unsigned short*)alloc((size_t)VDIM * DIMM * 2);
    unsigned short* Wevb  = (unsigned short*)alloc((size_t)VDIM * DIMM * 2);
    unsigned short* Woutb = (unsigned short*)alloc((size_t)DIMM * VDIM * 2);
    unsigned short* out2b = (unsigned short*)alloc((size_t)NN * VDIM * 2);
    int* slotCnt          = (int*)alloc(NN * 4);
    unsigned int* slots   = (unsigned int*)alloc((size_t)NN * SLOTW * 4);  // 512 KB
    (void)ws_size; (void)in_sizes; (void)n_in; (void)out_size;

    convert_init_kernel<<<1544, 256, 0, stream>>>(x, edges, Wq, Wk, Wv, Wev, Wout,
                                                  xb, eb, Wqb, Wkb, Wvb, Wevb, Woutb,
                                                  partialX, partialE, slotCnt);
    red_scatter_kernel<<<576, 256, 0, stream>>>(partialX, partialE, xsumG, esumG,
                                                ei32, slotCnt, slots);
    proj_gemv_kernel<<<1024, 256, 0, stream>>>(xb, eb, Wqb, Wkb, Wvb, Wevb, Pb,
                                               xsumG, esumG, Wv, Wev, colsum);
    laplacian_kernel<<<NN, 256, 0, stream>>>(slotCnt, slots, Wexp, colsum, Pb, out2b);
    outgemm_mfma_kernel<<<dim3(128, 4), 256, 0, stream>>>(out2b, Woutb, out);
}